// Round 17
// baseline (490.139 us; speedup 1.0000x reference)
//
#include <hip/hip_runtime.h>
#include <math.h>

#define H 4096
#define E 64
#define T_TOTAL 32768
#define TB 64             // tokens per block
#define NT 256            // 4 waves; tg = tid&15 (token quad), eg = tid>>4 (expert quad)
#define KC 128            // K per chunk (32 K4-steps)
#define NCH (H / KC)      // 32 chunks
#define NST (KC / 4)      // 32 steps per chunk
#define OFF_W 2097152
#define OFF_I 2162688

#define AS1 __attribute__((address_space(1)))
#define AS3 __attribute__((address_space(3)))

// Proven (R9/R12/R13/R15/R16 passed): 16B global->LDS DMA, linear LDS dest.
#define GLD16(SRC, DST)                                                      \
  __builtin_amdgcn_global_load_lds((const AS1 void*)(SRC), (AS3 void*)(DST), \
                                   16, 0, 0)

// R12-proven bank swizzle: logical col4 c of row r stored at slot c ^ swz(r)
// (4-bit swizzle; bit 4 of the 5-bit slot index passes through).
__device__ __forceinline__ int swz(int r) { return (r ^ (r >> 4)) & 15; }

// Issue step-S operand reads: x from LDS (pipe 1), W from global/L1 (pipe 2).
#define LOADS(XV, WV, S)                                                     \
  do {                                                                       \
    _Pragma("unroll")                                                        \
    for (int i = 0; i < 4; ++i)                                              \
      XV[i] = *(const float4*)(xp + (xbase[i] ^ ((S) << 2)));                \
    _Pragma("unroll")                                                        \
    for (int j = 0; j < 4; ++j)                                              \
      WV[j] = *(const float4*)(wrow[j] + kco + ((S) << 2));                  \
  } while (0)

// 64 FMAs on a resident register set. Ascending-K, x/y/z/w per
// (token,expert) — bit-identical chain to the verified R1/R12/R16 kernels.
#define FMAS(XV, WV)                                                         \
  do {                                                                       \
    _Pragma("unroll")                                                        \
    for (int i = 0; i < 4; ++i)                                              \
      _Pragma("unroll")                                                      \
      for (int j = 0; j < 4; ++j) {                                          \
        acc[i][j] = fmaf(XV[i].x, WV[j].x, acc[i][j]);                       \
        acc[i][j] = fmaf(XV[i].y, WV[j].y, acc[i][j]);                       \
        acc[i][j] = fmaf(XV[i].z, WV[j].z, acc[i][j]);                       \
        acc[i][j] = fmaf(XV[i].w, WV[j].w, acc[i][j]);                       \
      }                                                                      \
  } while (0)

// Distance-2 pipeline: issue loads for step s+2 into the set freed at s-1,
// then FMA step s's set.
#define P2(SNEXT, XL, WL, XC, WC)                                            \
  do { LOADS(XL, WL, SNEXT); FMAS(XC, WC); } while (0)

__global__ __launch_bounds__(NT, 2)
void moe_router_kernel(const float* __restrict__ x,
                       const float* __restrict__ W,
                       float* __restrict__ out)
{
    // Double-buffered x tile only (W comes from L1). 64 KB -> 2 blocks/CU.
    __shared__ float xt[2][TB * KC];

    const int tid  = threadIdx.x;
    const int tg   = tid & 15;          // token quad 4tg..4tg+3
    const int eg   = tid >> 4;          // expert quad 4eg..4eg+3
    const int tok0 = blockIdx.x * TB;

    // ---- x DMA source map (rule 21: linear dest unit u, inverse-swz src) ----
    // unit u (0..2047): row = u>>5 (0..63), slot = u&31, col4 = slot^swz(row)
    const float* xsrc[8];
    int xdst[8];
#pragma unroll
    for (int k = 0; k < 8; ++k) {
        const int u   = tid + k * NT;
        const int row = u >> 5;
        const int c4  = (u & 31) ^ swz(row);
        xsrc[k] = x + (size_t)(tok0 + row) * H + (c4 << 2);
        xdst[k] = u * 4;
    }

    // ---- LDS read bases (step s reads base ^ (4*s); carry-free: base bits
    //      2..6 hold only swz<<2, s<<2 spans bits 2..6) ----
    int xbase[4];
#pragma unroll
    for (int i = 0; i < 4; ++i) {
        const int r = 4 * tg + i;
        xbase[i] = r * KC + (swz(r) << 2);
    }

    // ---- W global row pointers (per-lane distinct -> vector loads, L1-hot) ----
    const float* wrow[4];
#pragma unroll
    for (int j = 0; j < 4; ++j)
        wrow[j] = W + (size_t)(4 * eg + j) * H;

    float acc[4][4];
#pragma unroll
    for (int i = 0; i < 4; ++i)
#pragma unroll
        for (int j = 0; j < 4; ++j) acc[i][j] = 0.f;

    // ---- prologue: DMA x chunk 0 into buffer 0 ----
#pragma unroll
    for (int k = 0; k < 8; ++k) GLD16(xsrc[k], &xt[0][xdst[k]]);
    __syncthreads();   // compiler drains vmcnt before s_barrier

    for (int c = 0; c < NCH; ++c) {
        const int b = c & 1;
        const int kco = c * KC;

        // DMA next x chunk into the other buffer (retired by barrier below)
        if (c + 1 < NCH) {
#pragma unroll
            for (int k = 0; k < 8; ++k)
                GLD16(xsrc[k] + (c + 1) * KC, &xt[b ^ 1][xdst[k]]);
        }

        // ---- 32 K4 steps, distance-2 pipeline (x: LDS pipe, W: L1 pipe) ----
        const float* xp = &xt[b][0];
        float4 xA[4], wA[4], xB[4], wB[4], xC[4], wC[4];

        LOADS(xA, wA, 0);
        LOADS(xB, wB, 1);
        P2(2,  xC, wC, xA, wA);   // s=0
        P2(3,  xA, wA, xB, wB);   // s=1
        P2(4,  xB, wB, xC, wC);   // s=2
        P2(5,  xC, wC, xA, wA);   // s=3
        P2(6,  xA, wA, xB, wB);   // s=4
        P2(7,  xB, wB, xC, wC);   // s=5
        P2(8,  xC, wC, xA, wA);   // s=6
        P2(9,  xA, wA, xB, wB);   // s=7
        P2(10, xB, wB, xC, wC);   // s=8
        P2(11, xC, wC, xA, wA);   // s=9
        P2(12, xA, wA, xB, wB);   // s=10
        P2(13, xB, wB, xC, wC);   // s=11
        P2(14, xC, wC, xA, wA);   // s=12
        P2(15, xA, wA, xB, wB);   // s=13
        P2(16, xB, wB, xC, wC);   // s=14
        P2(17, xC, wC, xA, wA);   // s=15
        P2(18, xA, wA, xB, wB);   // s=16
        P2(19, xB, wB, xC, wC);   // s=17
        P2(20, xC, wC, xA, wA);   // s=18
        P2(21, xA, wA, xB, wB);   // s=19
        P2(22, xB, wB, xC, wC);   // s=20
        P2(23, xC, wC, xA, wA);   // s=21
        P2(24, xA, wA, xB, wB);   // s=22
        P2(25, xB, wB, xC, wC);   // s=23
        P2(26, xC, wC, xA, wA);   // s=24
        P2(27, xA, wA, xB, wB);   // s=25
        P2(28, xB, wB, xC, wC);   // s=26
        P2(29, xC, wC, xA, wA);   // s=27
        P2(30, xA, wA, xB, wB);   // s=28
        P2(31, xB, wB, xC, wC);   // s=29
        FMAS(xA, wA);             // s=30
        FMAS(xB, wB);             // s=31

        __syncthreads();   // chunk c reads done; chunk c+1 DMA retired
    }

    // ---- logits out (coalesced float4 per owned token) ----
#pragma unroll
    for (int i = 0; i < 4; ++i) {
        float4 v; v.x = acc[i][0]; v.y = acc[i][1]; v.z = acc[i][2]; v.w = acc[i][3];
        *(float4*)(out + (size_t)(tok0 + 4 * tg + i) * E + 4 * eg) = v;
    }

    // ---- exchange for top-2 (reuse xt; 64 x 65 tile) ----
    float* lt = &xt[0][0];
#pragma unroll
    for (int i = 0; i < 4; ++i)
#pragma unroll
        for (int j = 0; j < 4; ++j)
            lt[(4 * tg + i) * 65 + 4 * eg + j] = acc[i][j];
    __syncthreads();

    if (tid < TB) {
        const float* row = lt + tid * 65;
        float v1 = -INFINITY, v2 = -INFINITY;
        int i1 = 0, i2 = 0;
        for (int e = 0; e < E; ++e) {
            float v = row[e];
            if (v > v1)      { v2 = v1; i2 = i1; v1 = v; i1 = e; }
            else if (v > v2) { v2 = v;  i2 = e; }
        }
        // softmax -> top2 -> renorm == sigmoid of logit gap (Z cancels)
        float ee = expf(v2 - v1);
        float w1 = 1.0f / (1.0f + ee);
        float w2 = ee * w1;

        const size_t tok = (size_t)tok0 + tid;
        out[OFF_W + tok * 2]     = w1;
        out[OFF_W + tok * 2 + 1] = w2;
        out[OFF_I + tok * 2]     = (float)i1;
        out[OFF_I + tok * 2 + 1] = (float)i2;
    }
}

extern "C" void kernel_launch(void* const* d_in, const int* in_sizes, int n_in,
                              void* d_out, int out_size, void* d_ws, size_t ws_size,
                              hipStream_t stream) {
    const float* x = (const float*)d_in[0];
    const float* W = (const float*)d_in[1];
    float* out = (float*)d_out;

    dim3 grid(T_TOTAL / TB);   // 512 blocks -> 2 blocks/CU, 2 waves/SIMD
    dim3 block(NT);
    moe_router_kernel<<<grid, block, 0, stream>>>(x, W, out);
}

// Round 18
// 367.694 us; speedup vs baseline: 1.3330x; 1.3330x over previous
//
#include <hip/hip_runtime.h>
#include <math.h>

#define H 4096
#define E 64
#define T_TOTAL 32768
#define TB 64             // tokens per block
#define NT 256            // 4 waves; tg = tid&15 (token quad), eg = tid>>4 (expert quad)
#define KC 64             // K per chunk (16 K4-steps)
#define NCH (H / KC)      // 64 chunks
#define OFF_W 2097152
#define OFF_I 2162688

#define AS1 __attribute__((address_space(1)))
#define AS3 __attribute__((address_space(3)))

// Proven (R9/R12/R13/R15/R16 passed): 16B global->LDS DMA, linear LDS dest.
#define GLD16(SRC, DST)                                                      \
  __builtin_amdgcn_global_load_lds((const AS1 void*)(SRC), (AS3 void*)(DST), \
                                   16, 0, 0)

// R12-proven bank swizzle: logical col4 c of row r stored at slot c ^ swz(r).
__device__ __forceinline__ int swz(int r) { return (r ^ (r >> 4)) & 15; }

// Issue step-S operand reads: x from LDS (pipe 1), W from global/L1 (pipe 2).
#define LOADS(XV, WV, S)                                                     \
  do {                                                                       \
    _Pragma("unroll")                                                        \
    for (int i = 0; i < 4; ++i)                                              \
      XV[i] = *(const float4*)(xp + (xbase[i] ^ ((S) << 2)));                \
    _Pragma("unroll")                                                        \
    for (int j = 0; j < 4; ++j)                                              \
      WV[j] = *(const float4*)(wrow[j] + kco + ((S) << 2));                  \
  } while (0)

// 64 FMAs on a resident register set. Ascending-K, x/y/z/w per
// (token,expert) — bit-identical chain to the verified R1/R12/R16 kernels.
#define FMAS(XV, WV)                                                         \
  do {                                                                       \
    _Pragma("unroll")                                                        \
    for (int i = 0; i < 4; ++i)                                              \
      _Pragma("unroll")                                                      \
      for (int j = 0; j < 4; ++j) {                                          \
        acc[i][j] = fmaf(XV[i].x, WV[j].x, acc[i][j]);                       \
        acc[i][j] = fmaf(XV[i].y, WV[j].y, acc[i][j]);                       \
        acc[i][j] = fmaf(XV[i].z, WV[j].z, acc[i][j]);                       \
        acc[i][j] = fmaf(XV[i].w, WV[j].w, acc[i][j]);                       \
      }                                                                      \
  } while (0)

// Distance-2 pipeline: issue loads for step SNEXT into the freed set,
// then FMA the current step's set.
#define P2(SNEXT, XL, WL, XC, WC)                                            \
  do { LOADS(XL, WL, SNEXT); FMAS(XC, WC); } while (0)

__global__ __launch_bounds__(NT, 2)
void moe_router_kernel(const float* __restrict__ x,
                       const float* __restrict__ W,
                       float* __restrict__ out)
{
    // Double-buffered x tile only (W comes from L1). 32 KB -> 2 blocks/CU.
    __shared__ float xt[2][TB * KC];

    const int tid  = threadIdx.x;
    const int tg   = tid & 15;          // token quad 4tg..4tg+3
    const int eg   = tid >> 4;          // expert quad 4eg..4eg+3
    const int tok0 = blockIdx.x * TB;

    // ---- x DMA source map (rule 21: linear dest unit u, inverse-swz src) ----
    // unit u (0..1023): row = u>>4 (0..63), slot = u&15, col4 = slot^swz(row)
    const float* xsrc[4];
    int xdst[4];
#pragma unroll
    for (int k = 0; k < 4; ++k) {
        const int u   = tid + k * NT;
        const int row = u >> 4;
        const int c4  = (u & 15) ^ swz(row);
        xsrc[k] = x + (size_t)(tok0 + row) * H + (c4 << 2);
        xdst[k] = u * 4;
    }

    // ---- LDS read bases (step s reads base ^ (4*s), carry-free 4-bit XOR) ----
    int xbase[4];
#pragma unroll
    for (int i = 0; i < 4; ++i) {
        const int r = 4 * tg + i;
        xbase[i] = r * KC + (swz(r) << 2);
    }

    // ---- W global row pointers (per-lane distinct -> vector loads, L1-hot) ----
    const float* wrow[4];
#pragma unroll
    for (int j = 0; j < 4; ++j)
        wrow[j] = W + (size_t)(4 * eg + j) * H;

    float acc[4][4];
#pragma unroll
    for (int i = 0; i < 4; ++i)
#pragma unroll
        for (int j = 0; j < 4; ++j) acc[i][j] = 0.f;

    // ---- prologue: DMA x chunk 0 into buffer 0 ----
#pragma unroll
    for (int k = 0; k < 4; ++k) GLD16(xsrc[k], &xt[0][xdst[k]]);
    __syncthreads();   // compiler drains vmcnt before s_barrier

    for (int c = 0; c < NCH; ++c) {
        const int b = c & 1;
        const int kco = c * KC;

        // DMA next x chunk into the other buffer (retired by barrier below)
        if (c + 1 < NCH) {
#pragma unroll
            for (int k = 0; k < 4; ++k)
                GLD16(xsrc[k] + (c + 1) * KC, &xt[b ^ 1][xdst[k]]);
        }

        // ---- 16 K4 steps, distance-2 pipeline (x: LDS pipe, W: L1 pipe) ----
        const float* xp = &xt[b][0];
        float4 xA[4], wA[4], xB[4], wB[4], xC[4], wC[4];

        LOADS(xA, wA, 0);
        LOADS(xB, wB, 1);
        P2(2,  xC, wC, xA, wA);   // s=0
        P2(3,  xA, wA, xB, wB);   // s=1
        P2(4,  xB, wB, xC, wC);   // s=2
        P2(5,  xC, wC, xA, wA);   // s=3
        P2(6,  xA, wA, xB, wB);   // s=4
        P2(7,  xB, wB, xC, wC);   // s=5
        P2(8,  xC, wC, xA, wA);   // s=6
        P2(9,  xA, wA, xB, wB);   // s=7
        P2(10, xB, wB, xC, wC);   // s=8
        P2(11, xC, wC, xA, wA);   // s=9
        P2(12, xA, wA, xB, wB);   // s=10
        P2(13, xB, wB, xC, wC);   // s=11
        P2(14, xC, wC, xA, wA);   // s=12
        P2(15, xA, wA, xB, wB);   // s=13
        FMAS(xC, wC);             // s=14
        FMAS(xA, wA);             // s=15

        __syncthreads();   // chunk c reads done; chunk c+1 DMA retired
    }

    // ---- logits out (coalesced float4 per owned token) ----
#pragma unroll
    for (int i = 0; i < 4; ++i) {
        float4 v; v.x = acc[i][0]; v.y = acc[i][1]; v.z = acc[i][2]; v.w = acc[i][3];
        *(float4*)(out + (size_t)(tok0 + 4 * tg + i) * E + 4 * eg) = v;
    }

    // ---- exchange for top-2 (reuse xt; 64 x 65 tile) ----
    float* lt = &xt[0][0];
#pragma unroll
    for (int i = 0; i < 4; ++i)
#pragma unroll
        for (int j = 0; j < 4; ++j)
            lt[(4 * tg + i) * 65 + 4 * eg + j] = acc[i][j];
    __syncthreads();

    if (tid < TB) {
        const float* row = lt + tid * 65;
        float v1 = -INFINITY, v2 = -INFINITY;
        int i1 = 0, i2 = 0;
        for (int e = 0; e < E; ++e) {
            float v = row[e];
            if (v > v1)      { v2 = v1; i2 = i1; v1 = v; i1 = e; }
            else if (v > v2) { v2 = v;  i2 = e; }
        }
        // softmax -> top2 -> renorm == sigmoid of logit gap (Z cancels)
        float ee = expf(v2 - v1);
        float w1 = 1.0f / (1.0f + ee);
        float w2 = ee * w1;

        const size_t tok = (size_t)tok0 + tid;
        out[OFF_W + tok * 2]     = w1;
        out[OFF_W + tok * 2 + 1] = w2;
        out[OFF_I + tok * 2]     = (float)i1;
        out[OFF_I + tok * 2 + 1] = (float)i2;
    }
}

extern "C" void kernel_launch(void* const* d_in, const int* in_sizes, int n_in,
                              void* d_out, int out_size, void* d_ws, size_t ws_size,
                              hipStream_t stream) {
    const float* x = (const float*)d_in[0];
    const float* W = (const float*)d_in[1];
    float* out = (float*)d_out;

    dim3 grid(T_TOTAL / TB);   // 512 blocks -> 2 blocks/CU, 2 waves/SIMD
    dim3 block(NT);
    moe_router_kernel<<<grid, block, 0, stream>>>(x, W, out);
}